// Round 1
// 7125.011 us; speedup vs baseline: 1.9369x; 1.9369x over previous
//
#include <hip/hip_runtime.h>
#include <cstdint>
#include <cstddef>

#define T_STEPS 512
#define BB 64
#define NIN 1024
#define HB 1024
#define NGC 4096
#define GBLK 128
#define HC 8
#define WLD 2056   // padded k-stride (bf16 elems) for LDS W tile

typedef __attribute__((ext_vector_type(8))) short short8;
typedef __attribute__((ext_vector_type(4))) float float4v;
typedef __attribute__((ext_vector_type(2))) float float2v;

__device__ __forceinline__ unsigned short f2bf(float f) {
    union { float f; unsigned u; } v; v.f = f;
    unsigned r = v.u + 0x7fffu + ((v.u >> 16) & 1u);   // RNE
    return (unsigned short)(r >> 16);
}

union S8U { short8 v; unsigned short u[8]; };

// ---- one-time fp32 -> bf16 conversion: X -> Xb (nxb blocks) and y0 -> ybuf1 (tail blocks) ----
__global__ void __launch_bounds__(256) cvt_kernel(const float* __restrict__ X,
                                                  unsigned short* __restrict__ Xb,
                                                  const float* __restrict__ y0,
                                                  unsigned short* __restrict__ yb1,
                                                  int nxb) {
    const int blk = blockIdx.x;
    const float* src; unsigned short* dst; size_t i;
    if (blk < nxb) { src = X;  dst = Xb;  i = ((size_t)blk * 256 + threadIdx.x) * 8; }
    else           { src = y0; dst = yb1; i = ((size_t)(blk - nxb) * 256 + threadIdx.x) * 8; }
    float4v a = *(const float4v*)(src + i);
    float4v b = *(const float4v*)(src + i + 4);
    S8U o;
    o.u[0] = f2bf(a[0]); o.u[1] = f2bf(a[1]); o.u[2] = f2bf(a[2]); o.u[3] = f2bf(a[3]);
    o.u[4] = f2bf(b[0]); o.u[5] = f2bf(b[1]); o.u[6] = f2bf(b[2]); o.u[7] = f2bf(b[3]);
    *(short8*)(dst + i) = o.v;
}

// ---- persistent LSTM scan: 128 blocks, W resident in LDS (bf16).
//      Recurrent y exchanged as bf16 via MALL (sc0 sc1 write-through stores / bypass loads):
//      NO buffer_wbl2 / buffer_inv fences, L2 keeps Xb resident across steps. ----
template<int XBF>
__global__ void __launch_bounds__(256, 1)
lstm_scan(const float* __restrict__ X, const unsigned short* __restrict__ Xb,
          const float* __restrict__ W, const float* __restrict__ bias,
          const float* __restrict__ y0, const float* __restrict__ c0,
          const float* __restrict__ imask, float* __restrict__ out,
          unsigned* __restrict__ bar)
{
    extern __shared__ char smem[];
    unsigned short* Wl = (unsigned short*)smem;            // [32][WLD] bf16
    float* zl = (float*)(smem + 32 * WLD * 2);             // [64][33]
    float* cl = zl + 64 * 33;                              // [64][8]
    float* bl = cl + 64 * 8;                               // [32]

    const int g   = blockIdx.x;
    const int tid = threadIdx.x;

    // --- init: W slice -> LDS bf16.  Local col j = gate*8 + c  <->  global col gate*1024 + g*8 + c
    for (int task = tid; task < 2048 * 4; task += 256) {
        int k = task >> 2, gt = task & 3;
        const float* src = W + (size_t)k * NGC + (size_t)gt * HB + (size_t)g * HC;
        #pragma unroll
        for (int c = 0; c < 8; ++c)
            Wl[(gt * 8 + c) * WLD + k] = f2bf(src[c]);
    }
    if (tid < 32) {
        int gt = tid >> 3, c = tid & 7;
        bl[tid] = bias[gt * HB + g * HC + c];
    }
    for (int p = tid; p < 512; p += 256) {
        int r = p >> 3, c = p & 7;
        cl[r * 8 + c] = c0[(size_t)r * HB + g * HC + c];
    }
    __syncthreads();

    const int w = tid >> 6, l = tid & 63;
    const int m16 = l & 15, q = l >> 4;
    const int arow = w * 16 + m16;      // batch row this lane supplies
    const int koff = q * 8;             // k offset inside 32-wide k-block
    const unsigned short* wl0 = Wl + (size_t)m16 * WLD + koff;         // cols 0..15
    const unsigned short* wl1 = Wl + (size_t)(16 + m16) * WLD + koff;  // cols 16..31

    float* Yout  = out;
    float* Cout  = out + (size_t)T_STEPS * BB * HB;
    float* cTout = Cout + (size_t)T_STEPS * BB * HB;
    // ybuf double-buffer lives in the cT region (exactly 2*64*1024 bf16 = 256 KB = cT fp32 size).
    unsigned short* yb0 = (unsigned short*)cTout;
    unsigned short* yb1 = yb0 + BB * HB;

    // gate-phase cell assignment: thread -> (row gr, cols gc, gc+1)
    const int gr = tid >> 2;
    const int gc = (tid & 3) << 1;

    for (int t = 0; t < T_STEPS; ++t) {
        float4v acc0 = {0.f, 0.f, 0.f, 0.f};
        float4v acc1 = {0.f, 0.f, 0.f, 0.f};

        // prefetch imask early (off critical path)
        float mrow = imask[(size_t)t * BB + gr];

        // ---- x_t @ Wx  (k = 0..1023) — independent of recurrence: runs BEFORE the barrier wait ----
        if (XBF) {
            const unsigned short* xs = Xb + ((size_t)t * BB + arow) * NIN + koff;
            short8 abuf[8];
            #pragma unroll
            for (int p = 0; p < 8; ++p) abuf[p] = *(const short8*)(xs + p * 32);
            #pragma unroll
            for (int kb = 0; kb < 32; ++kb) {
                short8 a = abuf[kb & 7];
                if (kb + 8 < 32) abuf[kb & 7] = *(const short8*)(xs + (kb + 8) * 32);
                short8 b0 = *(const short8*)(wl0 + kb * 32);
                short8 b1 = *(const short8*)(wl1 + kb * 32);
                acc0 = __builtin_amdgcn_mfma_f32_16x16x32_bf16(a, b0, acc0, 0, 0, 0);
                acc1 = __builtin_amdgcn_mfma_f32_16x16x32_bf16(a, b1, acc1, 0, 0, 0);
            }
        } else {
            const float* xs = X + ((size_t)t * BB + arow) * NIN + koff;
            float4v fb0[4], fb1[4];
            #pragma unroll
            for (int p = 0; p < 4; ++p) {
                fb0[p] = *(const float4v*)(xs + p * 32);
                fb1[p] = *(const float4v*)(xs + p * 32 + 4);
            }
            #pragma unroll
            for (int kb = 0; kb < 32; ++kb) {
                float4v f0 = fb0[kb & 3], f1 = fb1[kb & 3];
                if (kb + 4 < 32) {
                    fb0[kb & 3] = *(const float4v*)(xs + (kb + 4) * 32);
                    fb1[kb & 3] = *(const float4v*)(xs + (kb + 4) * 32 + 4);
                }
                S8U o;
                o.u[0] = f2bf(f0[0]); o.u[1] = f2bf(f0[1]); o.u[2] = f2bf(f0[2]); o.u[3] = f2bf(f0[3]);
                o.u[4] = f2bf(f1[0]); o.u[5] = f2bf(f1[1]); o.u[6] = f2bf(f1[2]); o.u[7] = f2bf(f1[3]);
                short8 b0 = *(const short8*)(wl0 + kb * 32);
                short8 b1 = *(const short8*)(wl1 + kb * 32);
                acc0 = __builtin_amdgcn_mfma_f32_16x16x32_bf16(o.v, b0, acc0, 0, 0, 0);
                acc1 = __builtin_amdgcn_mfma_f32_16x16x32_bf16(o.v, b1, acc1, 0, 0, 0);
            }
        }

        // ---- wait for y_{t-1} published (all blocks signaled end of step t-1) ----
        if (t > 0) {
            if (tid == 0) {
                const unsigned tgt = (unsigned)t * GBLK;
                while (__hip_atomic_load(bar, __ATOMIC_RELAXED, __HIP_MEMORY_SCOPE_AGENT) < tgt)
                    __builtin_amdgcn_s_sleep(1);
            }
            __syncthreads();
        }

        // ---- y_{t-1} @ Wh: bf16 broadcast buffer, cache-bypass loads, all 32 in flight ----
        {
            const unsigned short* ybr = ((t & 1) ? yb0 : yb1) + (size_t)arow * HB + koff;
            short8 yreg[32];
            #pragma unroll
            for (int kb = 0; kb < 32; ++kb)
                asm volatile("global_load_dwordx4 %0, %1, off offset:%2 sc0 sc1"
                             : "=v"(yreg[kb]) : "v"(ybr), "i"(kb * 64));
            asm volatile("s_waitcnt vmcnt(0)" ::: "memory");
            __builtin_amdgcn_sched_barrier(0);   // rule #18: keep MFMAs below the waitcnt
            #pragma unroll
            for (int kb = 0; kb < 32; ++kb) {
                short8 b0 = *(const short8*)(wl0 + 1024 + kb * 32);
                short8 b1 = *(const short8*)(wl1 + 1024 + kb * 32);
                acc0 = __builtin_amdgcn_mfma_f32_16x16x32_bf16(yreg[kb], b0, acc0, 0, 0, 0);
                acc1 = __builtin_amdgcn_mfma_f32_16x16x32_bf16(yreg[kb], b1, acc1, 0, 0, 0);
            }
        }

        // ---- z -> LDS (C/D layout: col=lane&15, row=quad*4+reg) ----
        #pragma unroll
        for (int i2 = 0; i2 < 4; ++i2) {
            int r = w * 16 + q * 4 + i2;
            zl[r * 33 + m16]      = acc0[i2];
            zl[r * 33 + 16 + m16] = acc1[i2];
        }

        // ---- extra grid barrier before last step's gate phase: cT region aliases ybuf,
        //      all blocks must finish their y_{510} reads before anyone writes cT ----
        if (t == T_STEPS - 1) {
            __syncthreads();
            if (tid == 0) {
                __hip_atomic_fetch_add(bar, 1u, __ATOMIC_RELAXED, __HIP_MEMORY_SCOPE_AGENT);
                const unsigned tgt = (unsigned)T_STEPS * GBLK;
                while (__hip_atomic_load(bar, __ATOMIC_RELAXED, __HIP_MEMORY_SCOPE_AGENT) < tgt)
                    __builtin_amdgcn_s_sleep(1);
            }
        }
        __syncthreads();

        // ---- gates: thread handles cells (gr, gc) and (gr, gc+1) ----
        {
            const int r = gr, c = gc;
            float z00 = zl[r * 33 + c]      + bl[c];
            float z01 = zl[r * 33 + c + 1]  + bl[c + 1];
            float z10 = zl[r * 33 + 8 + c]  + bl[8 + c];
            float z11 = zl[r * 33 + 9 + c]  + bl[9 + c];
            float z20 = zl[r * 33 + 16 + c] + bl[16 + c];
            float z21 = zl[r * 33 + 17 + c] + bl[17 + c];
            float z30 = zl[r * 33 + 24 + c] + bl[24 + c];
            float z31 = zl[r * 33 + 25 + c] + bl[25 + c];
            float cp0 = cl[r * 8 + c], cp1 = cl[r * 8 + c + 1];
            float m = mrow;
            float cell0 = tanhf(z00),                 cell1 = tanhf(z01);
            float ig0 = 1.f / (1.f + __expf(-z10)),   ig1 = 1.f / (1.f + __expf(-z11));
            float fg0 = 1.f / (1.f + __expf(-z20)),   fg1 = 1.f / (1.f + __expf(-z21));
            float og0 = 1.f / (1.f + __expf(-z30)),   og1 = 1.f / (1.f + __expf(-z31));
            float cn0 = cell0 * ig0 + cp0 * fg0,      cn1 = cell1 * ig1 + cp1 * fg1;
            float yn0 = tanhf(cn0) * og0,             yn1 = tanhf(cn1) * og1;  // y from pre-mask c
            cn0 = m * cn0 + (1.f - m) * cp0;          cn1 = m * cn1 + (1.f - m) * cp1;
            yn0 *= m;                                 yn1 *= m;
            cl[r * 8 + c] = cn0; cl[r * 8 + c + 1] = cn1;

            if (t < T_STEPS - 1) {
                // publish y_t as bf16 (write-through to MALL), then signal
                unsigned short* ybw = ((t & 1) ? yb1 : yb0) + (size_t)r * HB + (size_t)g * HC + c;
                unsigned pk = (unsigned)f2bf(yn0) | ((unsigned)f2bf(yn1) << 16);
                asm volatile("global_store_dword %0, %1, off sc0 sc1" :: "v"(ybw), "v"(pk) : "memory");
                asm volatile("s_waitcnt vmcnt(0)" ::: "memory");   // y_t globally visible
                __syncthreads();                                   // all threads' stores landed
                if (tid == 0)
                    __hip_atomic_fetch_add(bar, 1u, __ATOMIC_RELAXED, __HIP_MEMORY_SCOPE_AGENT);
            }

            // fp32 outputs: cached stores, off the critical path (issued after the signal)
            size_t oidx = ((size_t)t * BB + r) * HB + (size_t)g * HC + c;
            float2v yv = {yn0, yn1}; *(float2v*)(Yout + oidx) = yv;
            float2v cv = {cn0, cn1}; *(float2v*)(Cout + oidx) = cv;
            if (t == T_STEPS - 1) {
                float2v ct = {cn0, cn1};
                *(float2v*)(cTout + (size_t)r * HB + (size_t)g * HC + c) = ct;
            }
        }
    }
}

extern "C" void kernel_launch(void* const* d_in, const int* in_sizes, int n_in,
                              void* d_out, int out_size, void* d_ws, size_t ws_size,
                              hipStream_t stream) {
    const float* X    = (const float*)d_in[0];
    const float* W    = (const float*)d_in[1];
    const float* bias = (const float*)d_in[2];
    const float* y0   = (const float*)d_in[3];
    const float* c0   = (const float*)d_in[4];
    const float* im   = (const float*)d_in[5];
    float* out = (float*)d_out;

    unsigned* bar = (unsigned*)d_ws;
    unsigned short* Xb = (unsigned short*)((char*)d_ws + 256);
    const size_t xbytes = (size_t)T_STEPS * BB * NIN * sizeof(unsigned short);
    const int use_bf = (ws_size >= 256 + xbytes) ? 1 : 0;

    // ybuf double-buffer aliases the cT region of out (exact 256 KB fit)
    unsigned short* yb0 = (unsigned short*)(out + (size_t)2 * T_STEPS * BB * HB);
    unsigned short* yb1 = yb0 + (size_t)BB * HB;

    const int smem_bytes = 32 * WLD * 2 + 64 * 33 * 4 + 64 * 8 * 4 + 32 * 4;  // 142,208 B

    hipMemsetAsync(d_ws, 0, 256, stream);   // zero barrier counter

    const int nxb = use_bf ? (T_STEPS * BB * NIN) / (256 * 8) : 0;  // 16384 or 0
    const int nyb = (BB * HB) / (256 * 8);                          // 32
    cvt_kernel<<<nxb + nyb, 256, 0, stream>>>(X, Xb, y0, yb1, nxb);

    if (use_bf) {
        hipFuncSetAttribute((const void*)lstm_scan<1>,
                            hipFuncAttributeMaxDynamicSharedMemorySize, smem_bytes);
        lstm_scan<1><<<GBLK, 256, smem_bytes, stream>>>(X, Xb, W, bias, y0, c0, im, out, bar);
    } else {
        hipFuncSetAttribute((const void*)lstm_scan<0>,
                            hipFuncAttributeMaxDynamicSharedMemorySize, smem_bytes);
        lstm_scan<0><<<GBLK, 256, smem_bytes, stream>>>(X, Xb, W, bias, y0, c0, im, out, bar);
    }
}

// Round 2
// 5336.510 us; speedup vs baseline: 2.5860x; 1.3351x over previous
//
#include <hip/hip_runtime.h>
#include <cstdint>
#include <cstddef>

#define T_STEPS 512
#define BB 64
#define NIN 1024
#define HB 1024
#define NGC 4096
#define NSCAN 128
#define HC 8
#define WLDH 1032          // padded k-stride (bf16 elems) for LDS W tile
#define DRING 16           // Zx ring depth (slices)

typedef __attribute__((ext_vector_type(8))) short short8;
typedef __attribute__((ext_vector_type(4))) float float4v;
typedef __attribute__((ext_vector_type(2))) float float2v;

__device__ __forceinline__ unsigned short f2bf(float f) {
    union { float f; unsigned u; } v; v.f = f;
    unsigned r = v.u + 0x7fffu + ((v.u >> 16) & 1u);   // RNE
    return (unsigned short)(r >> 16);
}

union S8U { short8 v; unsigned short u[8]; unsigned w[4]; };

// ---- one-time y0 fp32 -> bf16 into ybuf1 (cT region of out) ----
__global__ void __launch_bounds__(256) cvt_y0_kernel(const float* __restrict__ y0,
                                                     unsigned short* __restrict__ yb1) {
    size_t i = ((size_t)blockIdx.x * 256 + threadIdx.x) * 8;
    float4v a = *(const float4v*)(y0 + i);
    float4v b = *(const float4v*)(y0 + i + 4);
    S8U o;
    o.u[0] = f2bf(a[0]); o.u[1] = f2bf(a[1]); o.u[2] = f2bf(a[2]); o.u[3] = f2bf(a[3]);
    o.u[4] = f2bf(b[0]); o.u[5] = f2bf(b[1]); o.u[6] = f2bf(b[2]); o.u[7] = f2bf(b[3]);
    *(short8*)(yb1 + i) = o.v;
}

// ---- fused persistent kernel: blocks 0..127 = scanners, 128..255 = feeders ----
__global__ void __launch_bounds__(256, 1)
lstm_fused(const float* __restrict__ X, const float* __restrict__ W,
           const float* __restrict__ bias, const float* __restrict__ y0,
           const float* __restrict__ c0, const float* __restrict__ imask,
           float* __restrict__ out, unsigned* __restrict__ prog,
           float* __restrict__ zring)
{
    extern __shared__ char smem[];
    unsigned short* Wl = (unsigned short*)smem;            // [32][WLDH] bf16
    float* zl = (float*)(smem + 32 * WLDH * 2);            // [64][33]
    float* cl = zl + 64 * 33;                              // [64][8]
    float* bl = cl + 64 * 8;                               // [32]

    const int bid = blockIdx.x;
    const bool is_scan = bid < NSCAN;
    const int g   = is_scan ? bid : bid - NSCAN;
    const int tid = threadIdx.x;

    // --- W slice -> LDS bf16.  Scan: Wh rows (k+1024); feeder: Wx rows (k).
    //     Local col j = gate*8 + c  <->  global col gate*1024 + g*8 + c
    {
        const int kbase = is_scan ? NIN : 0;
        for (int task = tid; task < 1024 * 4; task += 256) {
            int k = task >> 2, gt = task & 3;
            const float* src = W + (size_t)(kbase + k) * NGC + (size_t)gt * HB + (size_t)g * HC;
            #pragma unroll
            for (int c = 0; c < 8; ++c)
                Wl[(gt * 8 + c) * WLDH + k] = f2bf(src[c]);
        }
    }
    if (is_scan) {
        if (tid < 32) {
            int gt = tid >> 3, c = tid & 7;
            bl[tid] = bias[gt * HB + g * HC + c];
        }
        for (int p = tid; p < 512; p += 256) {
            int r = p >> 3, c = p & 7;
            cl[r * 8 + c] = c0[(size_t)r * HB + g * HC + c];
        }
    }
    __syncthreads();

    const int w = tid >> 6, l = tid & 63;
    const int m16 = l & 15, q = l >> 4;
    const int arow = w * 16 + m16;
    const int koff = q * 8;
    const unsigned short* wl0 = Wl + (size_t)m16 * WLDH + koff;         // local cols 0..15
    const unsigned short* wl1 = Wl + (size_t)(16 + m16) * WLDH + koff;  // local cols 16..31

    if (!is_scan) {
        // ================= FEEDER: Zx[t] cols [g*32, g*32+32) into ring =================
        unsigned* fslot = prog + NSCAN + g;
        unsigned* sslot = prog + g;
        for (int t = 0; t < T_STEPS; ++t) {
            float4v acc0 = {0.f, 0.f, 0.f, 0.f};
            float4v acc1 = {0.f, 0.f, 0.f, 0.f};
            const float* xs = X + ((size_t)t * BB + arow) * NIN + koff;
            float4v fbv0[4], fbv1[4];
            #pragma unroll
            for (int p = 0; p < 4; ++p) {
                fbv0[p] = *(const float4v*)(xs + p * 32);
                fbv1[p] = *(const float4v*)(xs + p * 32 + 4);
            }
            #pragma unroll
            for (int kb = 0; kb < 32; ++kb) {
                float4v f0 = fbv0[kb & 3], f1 = fbv1[kb & 3];
                if (kb + 4 < 32) {
                    fbv0[kb & 3] = *(const float4v*)(xs + (kb + 4) * 32);
                    fbv1[kb & 3] = *(const float4v*)(xs + (kb + 4) * 32 + 4);
                }
                S8U o;
                o.u[0] = f2bf(f0[0]); o.u[1] = f2bf(f0[1]); o.u[2] = f2bf(f0[2]); o.u[3] = f2bf(f0[3]);
                o.u[4] = f2bf(f1[0]); o.u[5] = f2bf(f1[1]); o.u[6] = f2bf(f1[2]); o.u[7] = f2bf(f1[3]);
                short8 b0 = *(const short8*)(wl0 + kb * 32);
                short8 b1 = *(const short8*)(wl1 + kb * 32);
                acc0 = __builtin_amdgcn_mfma_f32_16x16x32_bf16(o.v, b0, acc0, 0, 0, 0);
                acc1 = __builtin_amdgcn_mfma_f32_16x16x32_bf16(o.v, b1, acc1, 0, 0, 0);
            }
            // anti-overwrite: ring slot t%DRING must be past scanner's consumption
            if (t >= DRING) {
                if (tid == 0) {
                    const unsigned tgt = (unsigned)(t - DRING + 1);
                    unsigned v;
                    while (1) {
                        asm volatile("global_load_dword %0, %1, off sc0 sc1\n\t"
                                     "s_waitcnt vmcnt(0)" : "=v"(v) : "v"(sslot) : "memory");
                        if (v >= tgt) break;
                        __builtin_amdgcn_s_sleep(2);
                    }
                }
                __syncthreads();
            }
            // store 64x32 f32 slice (C/D layout: col=m16(+16), row=w*16+q*4+i2)
            float* zdst = zring + ((size_t)(t % DRING) * NSCAN + g) * 2048;
            #pragma unroll
            for (int i2 = 0; i2 < 4; ++i2) {
                float* p0 = zdst + (size_t)(w * 16 + q * 4 + i2) * 32 + m16;
                asm volatile("global_store_dword %0, %1, off sc0 sc1" :: "v"(p0), "v"(acc0[i2]) : "memory");
                asm volatile("global_store_dword %0, %1, off offset:64 sc0 sc1" :: "v"(p0), "v"(acc1[i2]) : "memory");
            }
            asm volatile("s_waitcnt vmcnt(0)" ::: "memory");
            __syncthreads();
            if (tid == 0) {
                unsigned v = (unsigned)(t + 1);
                asm volatile("global_store_dword %0, %1, off sc0 sc1" :: "v"(fslot), "v"(v) : "memory");
            }
        }
        return;
    }

    // ================= SCANNER =================
    float* Yout  = out;
    float* Cout  = out + (size_t)T_STEPS * BB * HB;
    float* cTout = Cout + (size_t)T_STEPS * BB * HB;
    unsigned short* yb0 = (unsigned short*)cTout;          // ybuf double-buffer aliases cT region
    unsigned short* yb1 = yb0 + BB * HB;

    const int gr = tid >> 2;            // gate-phase row 0..63
    const int gc = (tid & 3) << 1;      // gate-phase col pair 0,2,4,6

    const unsigned* pp0 = prog + l;            // poll addresses (wave0 lanes)
    const unsigned* pp1 = prog + 64 + l;
    const unsigned* ppf = prog + NSCAN + g;

    for (int t = 0; t < T_STEPS; ++t) {
        float mrow = imask[(size_t)t * BB + gr];   // cached, read-only

        // ---- wait: all scanners published y_{t-1} AND feeder g produced Zx[t] ----
        if (tid < 64) {
            unsigned a0, a1, ff;
            const unsigned st = (unsigned)t, ft = (unsigned)(t + 1);
            while (1) {
                asm volatile("global_load_dword %0, %1, off sc0 sc1" : "=v"(a0) : "v"(pp0));
                asm volatile("global_load_dword %0, %1, off sc0 sc1" : "=v"(a1) : "v"(pp1));
                asm volatile("global_load_dword %0, %1, off sc0 sc1" : "=v"(ff) : "v"(ppf));
                asm volatile("s_waitcnt vmcnt(0)" ::: "memory");
                bool ok = (a0 >= st) & (a1 >= st) & (ff >= ft);
                if (__ballot(ok) == ~0ull) break;
                __builtin_amdgcn_s_sleep(2);
            }
        }
        __syncthreads();

        // ---- issue y_{t-1} loads (32 in flight, MALL bypass) ----
        const unsigned short* ybr = ((t & 1) ? yb0 : yb1) + (size_t)arow * HB + koff;
        short8 yreg[32];
        #pragma unroll
        for (int kb = 0; kb < 32; ++kb)
            asm volatile("global_load_dwordx4 %0, %1, off offset:%2 sc0 sc1"
                         : "=v"(yreg[kb]) : "v"(ybr), "i"(kb * 64));
        // ---- issue Zx[t] register loads (land under y latency) ----
        const float* zp = zring + ((size_t)(t % DRING) * NSCAN + g) * 2048 + (size_t)gr * 32 + gc;
        float2v zx0, zx1, zx2, zx3;
        asm volatile("global_load_dwordx2 %0, %1, off sc0 sc1"            : "=v"(zx0) : "v"(zp));
        asm volatile("global_load_dwordx2 %0, %1, off offset:32 sc0 sc1"  : "=v"(zx1) : "v"(zp));
        asm volatile("global_load_dwordx2 %0, %1, off offset:64 sc0 sc1"  : "=v"(zx2) : "v"(zp));
        asm volatile("global_load_dwordx2 %0, %1, off offset:96 sc0 sc1"  : "=v"(zx3) : "v"(zp));

        // ---- prefetch first Wh fragments from LDS under the y MALL latency (lgkm, not vmcnt) ----
        short8 b0a[4], b1a[4];
        #pragma unroll
        for (int p = 0; p < 4; ++p) {
            b0a[p] = *(const short8*)(wl0 + p * 32);
            b1a[p] = *(const short8*)(wl1 + p * 32);
        }
        asm volatile("s_waitcnt vmcnt(0)" ::: "memory");
        __builtin_amdgcn_sched_barrier(0);   // rule #18: keep MFMAs below the waitcnt

        float4v acc0 = {0.f, 0.f, 0.f, 0.f};
        float4v acc1 = {0.f, 0.f, 0.f, 0.f};
        #pragma unroll
        for (int kb = 0; kb < 32; ++kb) {
            short8 b0 = b0a[kb & 3], b1 = b1a[kb & 3];
            if (kb + 4 < 32) {
                b0a[kb & 3] = *(const short8*)(wl0 + (kb + 4) * 32);
                b1a[kb & 3] = *(const short8*)(wl1 + (kb + 4) * 32);
            }
            acc0 = __builtin_amdgcn_mfma_f32_16x16x32_bf16(yreg[kb], b0, acc0, 0, 0, 0);
            acc1 = __builtin_amdgcn_mfma_f32_16x16x32_bf16(yreg[kb], b1, acc1, 0, 0, 0);
        }

        // ---- z(h-part) -> LDS (C/D layout: col=lane&15, row=quad*4+reg) ----
        #pragma unroll
        for (int i2 = 0; i2 < 4; ++i2) {
            int r = w * 16 + q * 4 + i2;
            zl[r * 33 + m16]      = acc0[i2];
            zl[r * 33 + 16 + m16] = acc1[i2];
        }
        __syncthreads();

        // ---- last step: cT region aliases ybuf — wait until ALL scanners finished y reads ----
        if (t == T_STEPS - 1) {
            if (tid == 0) {
                unsigned v = (unsigned)(T_STEPS + 1);   // sentinel 513
                asm volatile("global_store_dword %0, %1, off sc0 sc1" :: "v"(prog + g), "v"(v) : "memory");
            }
            if (tid < 64) {
                unsigned a0, a1;
                const unsigned st = (unsigned)(T_STEPS + 1);
                while (1) {
                    asm volatile("global_load_dword %0, %1, off sc0 sc1" : "=v"(a0) : "v"(pp0));
                    asm volatile("global_load_dword %0, %1, off sc0 sc1" : "=v"(a1) : "v"(pp1));
                    asm volatile("s_waitcnt vmcnt(0)" ::: "memory");
                    bool ok = (a0 >= st) & (a1 >= st);
                    if (__ballot(ok) == ~0ull) break;
                    __builtin_amdgcn_s_sleep(2);
                }
            }
            __syncthreads();
        }

        // ---- gates: thread -> (row gr, cols gc, gc+1); z = zl(h) + zx(x) + bias ----
        {
            const int r = gr, c = gc;
            float z00 = zl[r * 33 + c]      + zx0[0] + bl[c];
            float z01 = zl[r * 33 + c + 1]  + zx0[1] + bl[c + 1];
            float z10 = zl[r * 33 + 8 + c]  + zx1[0] + bl[8 + c];
            float z11 = zl[r * 33 + 9 + c]  + zx1[1] + bl[9 + c];
            float z20 = zl[r * 33 + 16 + c] + zx2[0] + bl[16 + c];
            float z21 = zl[r * 33 + 17 + c] + zx2[1] + bl[17 + c];
            float z30 = zl[r * 33 + 24 + c] + zx3[0] + bl[24 + c];
            float z31 = zl[r * 33 + 25 + c] + zx3[1] + bl[25 + c];
            float cp0 = cl[r * 8 + c], cp1 = cl[r * 8 + c + 1];
            float m = mrow;
            float cell0 = tanhf(z00),                 cell1 = tanhf(z01);
            float ig0 = 1.f / (1.f + __expf(-z10)),   ig1 = 1.f / (1.f + __expf(-z11));
            float fg0 = 1.f / (1.f + __expf(-z20)),   fg1 = 1.f / (1.f + __expf(-z21));
            float og0 = 1.f / (1.f + __expf(-z30)),   og1 = 1.f / (1.f + __expf(-z31));
            float cn0 = cell0 * ig0 + cp0 * fg0,      cn1 = cell1 * ig1 + cp1 * fg1;
            float yn0 = tanhf(cn0) * og0,             yn1 = tanhf(cn1) * og1;  // y from pre-mask c
            cn0 = m * cn0 + (1.f - m) * cp0;          cn1 = m * cn1 + (1.f - m) * cp1;
            yn0 *= m;                                 yn1 *= m;
            cl[r * 8 + c] = cn0; cl[r * 8 + c + 1] = cn1;

            if (t < T_STEPS - 1) {
                // publish y_t bf16 (write-through to MALL), ack, then slot-signal
                unsigned short* ybw = ((t & 1) ? yb1 : yb0) + (size_t)r * HB + (size_t)g * HC + c;
                unsigned pk = (unsigned)f2bf(yn0) | ((unsigned)f2bf(yn1) << 16);
                asm volatile("global_store_dword %0, %1, off sc0 sc1" :: "v"(ybw), "v"(pk) : "memory");
                asm volatile("s_waitcnt vmcnt(0)" ::: "memory");
                __syncthreads();
                if (tid == 0) {
                    unsigned v = (unsigned)(t + 1);
                    asm volatile("global_store_dword %0, %1, off sc0 sc1" :: "v"(prog + g), "v"(v) : "memory");
                }
            }

            // fp32 outputs: cached stores, off the critical path
            size_t oidx = ((size_t)t * BB + r) * HB + (size_t)g * HC + c;
            float2v yv = {yn0, yn1}; *(float2v*)(Yout + oidx) = yv;
            float2v cv = {cn0, cn1}; *(float2v*)(Cout + oidx) = cv;
            if (t == T_STEPS - 1) {
                float2v ct = {cn0, cn1};
                *(float2v*)(cTout + (size_t)r * HB + (size_t)g * HC + c) = ct;
            }
        }
    }
}

extern "C" void kernel_launch(void* const* d_in, const int* in_sizes, int n_in,
                              void* d_out, int out_size, void* d_ws, size_t ws_size,
                              hipStream_t stream) {
    const float* X    = (const float*)d_in[0];
    const float* W    = (const float*)d_in[1];
    const float* bias = (const float*)d_in[2];
    const float* y0   = (const float*)d_in[3];
    const float* c0   = (const float*)d_in[4];
    const float* im   = (const float*)d_in[5];
    float* out = (float*)d_out;

    unsigned* prog = (unsigned*)d_ws;                         // [256] progress slots
    float* zring   = (float*)((char*)d_ws + 4096);            // [DRING][128][64][32] f32 = 16 MB

    // ybuf double-buffer aliases the cT region of out (exact 256 KB fit)
    unsigned short* yb0 = (unsigned short*)(out + (size_t)2 * T_STEPS * BB * HB);
    unsigned short* yb1 = yb0 + (size_t)BB * HB;

    const int smem_bytes = 32 * WLDH * 2 + 64 * 33 * 4 + 64 * 8 * 4 + 32 * 4;  // 76,672 B

    hipMemsetAsync(d_ws, 0, 4096, stream);   // zero progress slots (ws poisoned each launch)

    cvt_y0_kernel<<<(BB * HB) / (256 * 8), 256, 0, stream>>>(y0, yb1);

    hipFuncSetAttribute((const void*)lstm_fused,
                        hipFuncAttributeMaxDynamicSharedMemorySize, smem_bytes);
    lstm_fused<<<2 * NSCAN, 256, smem_bytes, stream>>>(X, W, bias, y0, c0, im, out, prog, zring);
}

// Round 3
// 5274.345 us; speedup vs baseline: 2.6165x; 1.0118x over previous
//
#include <hip/hip_runtime.h>
#include <cstdint>
#include <cstddef>

#define T_STEPS 512
#define BB 64
#define NIN 1024
#define HB 1024
#define NGC 4096
#define NSCAN 128
#define HC 8
#define WLDH 1032          // padded k-stride (bf16 elems) for LDS W tile
#define DRING 16           // Zx ring depth (slices)

typedef __attribute__((ext_vector_type(8))) short short8;
typedef __attribute__((ext_vector_type(4))) float float4v;
typedef __attribute__((ext_vector_type(2))) float float2v;

__device__ __forceinline__ unsigned short f2bf(float f) {
    union { float f; unsigned u; } v; v.f = f;
    unsigned r = v.u + 0x7fffu + ((v.u >> 16) & 1u);   // RNE
    return (unsigned short)(r >> 16);
}

union S8U { short8 v; unsigned short u[8]; unsigned w[4]; };

// ---- one-time y0 fp32 -> bf16 into ybuf1 (cT region of out) ----
__global__ void __launch_bounds__(256) cvt_y0_kernel(const float* __restrict__ y0,
                                                     unsigned short* __restrict__ yb1) {
    size_t i = ((size_t)blockIdx.x * 256 + threadIdx.x) * 8;
    float4v a = *(const float4v*)(y0 + i);
    float4v b = *(const float4v*)(y0 + i + 4);
    S8U o;
    o.u[0] = f2bf(a[0]); o.u[1] = f2bf(a[1]); o.u[2] = f2bf(a[2]); o.u[3] = f2bf(a[3]);
    o.u[4] = f2bf(b[0]); o.u[5] = f2bf(b[1]); o.u[6] = f2bf(b[2]); o.u[7] = f2bf(b[3]);
    *(short8*)(yb1 + i) = o.v;
}

// ---- fused persistent kernel: blocks 0..127 = scanners, 128..255 = feeders ----
__global__ void __launch_bounds__(256, 1)
lstm_fused(const float* __restrict__ X, const float* __restrict__ W,
           const float* __restrict__ bias, const float* __restrict__ y0,
           const float* __restrict__ c0, const float* __restrict__ imask,
           float* __restrict__ out, unsigned* __restrict__ prog,
           float* __restrict__ zring)
{
    extern __shared__ char smem[];
    unsigned short* Wl = (unsigned short*)smem;            // [32][WLDH] bf16
    float* zl = (float*)(smem + 32 * WLDH * 2);            // [4][64][33] z partials (per wave)
    float* cl = zl + 4 * 64 * 33;                          // [64][8]
    float* bl = cl + 64 * 8;                               // [32]

    const int bid = blockIdx.x;
    const bool is_scan = bid < NSCAN;
    const int g   = is_scan ? bid : bid - NSCAN;
    const int tid = threadIdx.x;

    // --- W slice -> LDS bf16.  Scan: Wh rows (k+1024); feeder: Wx rows (k).
    //     Local col j = gate*8 + c  <->  global col gate*1024 + g*8 + c
    {
        const int kbase = is_scan ? NIN : 0;
        for (int task = tid; task < 1024 * 4; task += 256) {
            int k = task >> 2, gt = task & 3;
            const float* src = W + (size_t)(kbase + k) * NGC + (size_t)gt * HB + (size_t)g * HC;
            #pragma unroll
            for (int c = 0; c < 8; ++c)
                Wl[(gt * 8 + c) * WLDH + k] = f2bf(src[c]);
        }
    }
    if (is_scan) {
        if (tid < 32) {
            int gt = tid >> 3, c = tid & 7;
            bl[tid] = bias[gt * HB + g * HC + c];
        }
        for (int p = tid; p < 512; p += 256) {
            int r = p >> 3, c = p & 7;
            cl[r * 8 + c] = c0[(size_t)r * HB + g * HC + c];
        }
    }
    __syncthreads();

    const int w = tid >> 6, l = tid & 63;
    const int m16 = l & 15, q = l >> 4;
    const int koff = q * 8;

    if (!is_scan) {
        // ================= FEEDER: Zx[t] cols [g*32, g*32+32) into ring =================
        const unsigned short* wl0 = Wl + (size_t)m16 * WLDH + koff;         // cols 0..15
        const unsigned short* wl1 = Wl + (size_t)(16 + m16) * WLDH + koff;  // cols 16..31
        const int arow = w * 16 + m16;
        unsigned* fslot = prog + NSCAN + g;
        unsigned* sslot = prog + g;
        for (int t = 0; t < T_STEPS; ++t) {
            float4v acc0 = {0.f, 0.f, 0.f, 0.f};
            float4v acc1 = {0.f, 0.f, 0.f, 0.f};
            const float* xs = X + ((size_t)t * BB + arow) * NIN + koff;
            float4v fbv0[4], fbv1[4];
            #pragma unroll
            for (int p = 0; p < 4; ++p) {
                fbv0[p] = *(const float4v*)(xs + p * 32);
                fbv1[p] = *(const float4v*)(xs + p * 32 + 4);
            }
            #pragma unroll
            for (int kb = 0; kb < 32; ++kb) {
                float4v f0 = fbv0[kb & 3], f1 = fbv1[kb & 3];
                if (kb + 4 < 32) {
                    fbv0[kb & 3] = *(const float4v*)(xs + (kb + 4) * 32);
                    fbv1[kb & 3] = *(const float4v*)(xs + (kb + 4) * 32 + 4);
                }
                S8U o;
                o.u[0] = f2bf(f0[0]); o.u[1] = f2bf(f0[1]); o.u[2] = f2bf(f0[2]); o.u[3] = f2bf(f0[3]);
                o.u[4] = f2bf(f1[0]); o.u[5] = f2bf(f1[1]); o.u[6] = f2bf(f1[2]); o.u[7] = f2bf(f1[3]);
                short8 b0 = *(const short8*)(wl0 + kb * 32);
                short8 b1 = *(const short8*)(wl1 + kb * 32);
                acc0 = __builtin_amdgcn_mfma_f32_16x16x32_bf16(o.v, b0, acc0, 0, 0, 0);
                acc1 = __builtin_amdgcn_mfma_f32_16x16x32_bf16(o.v, b1, acc1, 0, 0, 0);
            }
            // anti-overwrite: ring slot t%DRING must be past scanner's consumption
            if (t >= DRING) {
                if (tid == 0) {
                    const unsigned tgt = (unsigned)(t - DRING + 1);
                    unsigned v;
                    while (1) {
                        asm volatile("global_load_dword %0, %1, off sc0 sc1\n\t"
                                     "s_waitcnt vmcnt(0)" : "=v"(v) : "v"(sslot) : "memory");
                        if (v >= tgt) break;
                        __builtin_amdgcn_s_sleep(2);
                    }
                }
                __syncthreads();
            }
            // store 64x32 f32 slice (C/D layout: col=m16(+16), row=w*16+q*4+i2)
            float* zdst = zring + ((size_t)(t % DRING) * NSCAN + g) * 2048;
            #pragma unroll
            for (int i2 = 0; i2 < 4; ++i2) {
                float* p0 = zdst + (size_t)(w * 16 + q * 4 + i2) * 32 + m16;
                asm volatile("global_store_dword %0, %1, off sc0 sc1" :: "v"(p0), "v"(acc0[i2]) : "memory");
                asm volatile("global_store_dword %0, %1, off offset:64 sc0 sc1" :: "v"(p0), "v"(acc1[i2]) : "memory");
            }
            asm volatile("s_waitcnt vmcnt(0)" ::: "memory");
            __syncthreads();
            if (tid == 0) {
                unsigned v = (unsigned)(t + 1);
                asm volatile("global_store_dword %0, %1, off sc0 sc1" :: "v"(fslot), "v"(v) : "memory");
            }
        }
        return;
    }

    // ================= SCANNER (k-split by wave: wave w owns k in [256w, 256w+256)) =================
    float* Yout  = out;
    float* Cout  = out + (size_t)T_STEPS * BB * HB;
    float* cTout = Cout + (size_t)T_STEPS * BB * HB;
    unsigned short* yb0 = (unsigned short*)cTout;          // ybuf double-buffer aliases cT region
    unsigned short* yb1 = yb0 + BB * HB;

    const int K0 = w * 256;                                // this wave's k-window base (elems)
    const unsigned short* wlA = Wl + (size_t)m16 * WLDH + K0 + koff;        // cols 0..15
    const unsigned short* wlB = Wl + (size_t)(16 + m16) * WLDH + K0 + koff; // cols 16..31
    float* zlw = zl + w * (64 * 33);                       // this wave's z partial

    const int gr = tid >> 2;            // gate-phase row 0..63
    const int gc = (tid & 3) << 1;      // gate-phase col pair 0,2,4,6

    const unsigned* pollp = prog + 32 * w + (l & 31);      // this wave's 32 producers
    const unsigned* ppf   = prog + NSCAN + g;              // feeder slot
    const unsigned* pp0 = prog + l;                        // sentinel-poll addrs (wave0 use)
    const unsigned* pp1 = prog + 64 + l;

    for (int t = 0; t < T_STEPS; ++t) {
        float mrow = imask[(size_t)t * BB + gr];   // cached, read-only

        // ---- Wh fragments for this wave's k-window: issue LDS reads BEFORE the poll ----
        short8 bf0[8], bf1[8];
        #pragma unroll
        for (int k2 = 0; k2 < 8; ++k2) {
            bf0[k2] = *(const short8*)(wlA + k2 * 32);
            bf1[k2] = *(const short8*)(wlB + k2 * 32);
        }

        // ---- per-wave poll: my 32 producers published y_{t-1}, my feeder produced Zx[t] ----
        {
            const unsigned st = (unsigned)t, ft = (unsigned)(t + 1);
            unsigned a0, ff;
            while (1) {
                asm volatile("global_load_dword %0, %1, off sc0 sc1" : "=v"(a0) : "v"(pollp));
                asm volatile("global_load_dword %0, %1, off sc0 sc1" : "=v"(ff) : "v"(ppf));
                asm volatile("s_waitcnt vmcnt(0)" ::: "memory");
                bool ok = (ff >= ft) && ((l >= 32) || (a0 >= st));
                if (__ballot(ok) == ~0ull) break;
                __builtin_amdgcn_s_sleep(1);
            }
        }

        // ---- y_{t-1} loads: 4 row-groups x 8 k-chunks of this wave's window (MALL bypass) ----
        const unsigned short* ybase = ((t & 1) ? yb0 : yb1);
        const unsigned short* p0 = ybase + (size_t)m16 * HB + K0 + koff;
        const unsigned short* p1 = p0 + 16 * HB;
        const unsigned short* p2 = p0 + 32 * HB;
        const unsigned short* p3 = p0 + 48 * HB;
        short8 yA[8], yB[8], yC[8], yD[8];
        #pragma unroll
        for (int k2 = 0; k2 < 8; ++k2) {
            asm volatile("global_load_dwordx4 %0, %1, off offset:%2 sc0 sc1" : "=v"(yA[k2]) : "v"(p0), "i"(k2 * 64));
            asm volatile("global_load_dwordx4 %0, %1, off offset:%2 sc0 sc1" : "=v"(yB[k2]) : "v"(p1), "i"(k2 * 64));
            asm volatile("global_load_dwordx4 %0, %1, off offset:%2 sc0 sc1" : "=v"(yC[k2]) : "v"(p2), "i"(k2 * 64));
            asm volatile("global_load_dwordx4 %0, %1, off offset:%2 sc0 sc1" : "=v"(yD[k2]) : "v"(p3), "i"(k2 * 64));
        }
        // ---- Zx[t] register loads (consumed in gates; land under y latency) ----
        const float* zp = zring + ((size_t)(t % DRING) * NSCAN + g) * 2048 + (size_t)gr * 32 + gc;
        float2v zx0, zx1, zx2, zx3;
        asm volatile("global_load_dwordx2 %0, %1, off sc0 sc1"            : "=v"(zx0) : "v"(zp));
        asm volatile("global_load_dwordx2 %0, %1, off offset:32 sc0 sc1"  : "=v"(zx1) : "v"(zp));
        asm volatile("global_load_dwordx2 %0, %1, off offset:64 sc0 sc1"  : "=v"(zx2) : "v"(zp));
        asm volatile("global_load_dwordx2 %0, %1, off offset:96 sc0 sc1"  : "=v"(zx3) : "v"(zp));

        asm volatile("s_waitcnt vmcnt(0) lgkmcnt(0)" ::: "memory");
        __builtin_amdgcn_sched_barrier(0);   // rule #18: keep MFMAs below the waitcnt

        // ---- 64 back-to-back MFMAs: 4 row-groups x 2 col-groups x 8 k-chunks ----
        float4v aA0 = {0.f,0.f,0.f,0.f}, aA1 = {0.f,0.f,0.f,0.f};
        float4v aB0 = {0.f,0.f,0.f,0.f}, aB1 = {0.f,0.f,0.f,0.f};
        float4v aC0 = {0.f,0.f,0.f,0.f}, aC1 = {0.f,0.f,0.f,0.f};
        float4v aD0 = {0.f,0.f,0.f,0.f}, aD1 = {0.f,0.f,0.f,0.f};
        #pragma unroll
        for (int k2 = 0; k2 < 8; ++k2) {
            short8 b0 = bf0[k2], b1 = bf1[k2];
            aA0 = __builtin_amdgcn_mfma_f32_16x16x32_bf16(yA[k2], b0, aA0, 0, 0, 0);
            aA1 = __builtin_amdgcn_mfma_f32_16x16x32_bf16(yA[k2], b1, aA1, 0, 0, 0);
            aB0 = __builtin_amdgcn_mfma_f32_16x16x32_bf16(yB[k2], b0, aB0, 0, 0, 0);
            aB1 = __builtin_amdgcn_mfma_f32_16x16x32_bf16(yB[k2], b1, aB1, 0, 0, 0);
            aC0 = __builtin_amdgcn_mfma_f32_16x16x32_bf16(yC[k2], b0, aC0, 0, 0, 0);
            aC1 = __builtin_amdgcn_mfma_f32_16x16x32_bf16(yC[k2], b1, aC1, 0, 0, 0);
            aD0 = __builtin_amdgcn_mfma_f32_16x16x32_bf16(yD[k2], b0, aD0, 0, 0, 0);
            aD1 = __builtin_amdgcn_mfma_f32_16x16x32_bf16(yD[k2], b1, aD1, 0, 0, 0);
        }

        // ---- z partial -> LDS (C/D layout: col=m16(+16), row=rg*16+q*4+i2) ----
        #pragma unroll
        for (int i2 = 0; i2 < 4; ++i2) {
            zlw[( 0 + q * 4 + i2) * 33 + m16]      = aA0[i2];
            zlw[( 0 + q * 4 + i2) * 33 + 16 + m16] = aA1[i2];
            zlw[(16 + q * 4 + i2) * 33 + m16]      = aB0[i2];
            zlw[(16 + q * 4 + i2) * 33 + 16 + m16] = aB1[i2];
            zlw[(32 + q * 4 + i2) * 33 + m16]      = aC0[i2];
            zlw[(32 + q * 4 + i2) * 33 + 16 + m16] = aC1[i2];
            zlw[(48 + q * 4 + i2) * 33 + m16]      = aD0[i2];
            zlw[(48 + q * 4 + i2) * 33 + 16 + m16] = aD1[i2];
        }
        __syncthreads();

        // ---- last step: cT region aliases ybuf — wait until ALL scanners finished y reads ----
        if (t == T_STEPS - 1) {
            if (tid == 0) {
                unsigned v = (unsigned)(T_STEPS + 1);   // sentinel 513
                asm volatile("global_store_dword %0, %1, off sc0 sc1" :: "v"(prog + g), "v"(v) : "memory");
            }
            if (tid < 64) {
                unsigned a0, a1;
                const unsigned st = (unsigned)(T_STEPS + 1);
                while (1) {
                    asm volatile("global_load_dword %0, %1, off sc0 sc1" : "=v"(a0) : "v"(pp0));
                    asm volatile("global_load_dword %0, %1, off sc0 sc1" : "=v"(a1) : "v"(pp1));
                    asm volatile("s_waitcnt vmcnt(0)" ::: "memory");
                    bool ok = (a0 >= st) & (a1 >= st);
                    if (__ballot(ok) == ~0ull) break;
                    __builtin_amdgcn_s_sleep(2);
                }
            }
            __syncthreads();
        }

        // ---- gates: thread -> (row gr, cols gc, gc+1); z = sum of 4 wave partials + zx + bias ----
        {
            const int r = gr, c = gc;
            const int rb = r * 33;
            #define ZS(o) (zl[(o)] + zl[2112 + (o)] + zl[4224 + (o)] + zl[6336 + (o)])
            float z00 = ZS(rb + c)      + zx0[0] + bl[c];
            float z01 = ZS(rb + c + 1)  + zx0[1] + bl[c + 1];
            float z10 = ZS(rb + 8 + c)  + zx1[0] + bl[8 + c];
            float z11 = ZS(rb + 9 + c)  + zx1[1] + bl[9 + c];
            float z20 = ZS(rb + 16 + c) + zx2[0] + bl[16 + c];
            float z21 = ZS(rb + 17 + c) + zx2[1] + bl[17 + c];
            float z30 = ZS(rb + 24 + c) + zx3[0] + bl[24 + c];
            float z31 = ZS(rb + 25 + c) + zx3[1] + bl[25 + c];
            #undef ZS
            float cp0 = cl[r * 8 + c], cp1 = cl[r * 8 + c + 1];
            float m = mrow;
            float cell0 = tanhf(z00),                 cell1 = tanhf(z01);
            float ig0 = 1.f / (1.f + __expf(-z10)),   ig1 = 1.f / (1.f + __expf(-z11));
            float fg0 = 1.f / (1.f + __expf(-z20)),   fg1 = 1.f / (1.f + __expf(-z21));
            float og0 = 1.f / (1.f + __expf(-z30)),   og1 = 1.f / (1.f + __expf(-z31));
            float cn0 = cell0 * ig0 + cp0 * fg0,      cn1 = cell1 * ig1 + cp1 * fg1;
            float yn0 = tanhf(cn0) * og0,             yn1 = tanhf(cn1) * og1;  // y from pre-mask c
            cn0 = m * cn0 + (1.f - m) * cp0;          cn1 = m * cn1 + (1.f - m) * cp1;
            yn0 *= m;                                 yn1 *= m;
            cl[r * 8 + c] = cn0; cl[r * 8 + c + 1] = cn1;

            if (t < T_STEPS - 1) {
                // publish y_t bf16 (write-through to MALL), ack, then slot-signal
                unsigned short* ybw = ((t & 1) ? yb1 : yb0) + (size_t)r * HB + (size_t)g * HC + c;
                unsigned pk = (unsigned)f2bf(yn0) | ((unsigned)f2bf(yn1) << 16);
                asm volatile("global_store_dword %0, %1, off sc0 sc1" :: "v"(ybw), "v"(pk) : "memory");
                asm volatile("s_waitcnt vmcnt(0)" ::: "memory");
                __syncthreads();
                if (tid == 0) {
                    unsigned v = (unsigned)(t + 1);
                    asm volatile("global_store_dword %0, %1, off sc0 sc1" :: "v"(prog + g), "v"(v) : "memory");
                }
            }

            // fp32 outputs: cached stores, off the critical path
            size_t oidx = ((size_t)t * BB + r) * HB + (size_t)g * HC + c;
            float2v yv = {yn0, yn1}; *(float2v*)(Yout + oidx) = yv;
            float2v cv = {cn0, cn1}; *(float2v*)(Cout + oidx) = cv;
            if (t == T_STEPS - 1) {
                float2v ct = {cn0, cn1};
                *(float2v*)(cTout + (size_t)r * HB + (size_t)g * HC + c) = ct;
            }
        }
    }
}

extern "C" void kernel_launch(void* const* d_in, const int* in_sizes, int n_in,
                              void* d_out, int out_size, void* d_ws, size_t ws_size,
                              hipStream_t stream) {
    const float* X    = (const float*)d_in[0];
    const float* W    = (const float*)d_in[1];
    const float* bias = (const float*)d_in[2];
    const float* y0   = (const float*)d_in[3];
    const float* c0   = (const float*)d_in[4];
    const float* im   = (const float*)d_in[5];
    float* out = (float*)d_out;

    unsigned* prog = (unsigned*)d_ws;                         // [256] progress slots
    float* zring   = (float*)((char*)d_ws + 4096);            // [DRING][128][64][32] f32 = 16 MB

    // ybuf double-buffer aliases the cT region of out (exact 256 KB fit)
    unsigned short* yb1 = (unsigned short*)(out + (size_t)2 * T_STEPS * BB * HB) + (size_t)BB * HB;

    const int smem_bytes = 32 * WLDH * 2 + 4 * 64 * 33 * 4 + 64 * 8 * 4 + 32 * 4;  // 102,016 B

    hipMemsetAsync(d_ws, 0, 4096, stream);   // zero progress slots (ws poisoned each launch)

    cvt_y0_kernel<<<(BB * HB) / (256 * 8), 256, 0, stream>>>(y0, yb1);

    hipFuncSetAttribute((const void*)lstm_fused,
                        hipFuncAttributeMaxDynamicSharedMemorySize, smem_bytes);
    lstm_fused<<<2 * NSCAN, 256, smem_bytes, stream>>>(X, W, bias, y0, c0, im, out, prog, zring);
}

// Round 4
// 5137.326 us; speedup vs baseline: 2.6863x; 1.0267x over previous
//
#include <hip/hip_runtime.h>
#include <cstdint>
#include <cstddef>

#define T_STEPS 512
#define BB 64
#define NIN 1024
#define HB 1024
#define NGC 4096
#define NSCAN 128
#define HC 8
#define WLDH 1032          // padded k-stride (bf16 elems) for LDS W tile
#define DRING 16           // Zx ring depth (slices)

typedef __attribute__((ext_vector_type(8))) short short8;
typedef __attribute__((ext_vector_type(4))) float float4v;
typedef __attribute__((ext_vector_type(2))) float float2v;

__device__ __forceinline__ unsigned short f2bf(float f) {
    union { float f; unsigned u; } v; v.f = f;
    unsigned r = v.u + 0x7fffu + ((v.u >> 16) & 1u);   // RNE
    return (unsigned short)(r >> 16);
}

union S8U { short8 v; unsigned short u[8]; unsigned w[4]; };

// ---- one-time fp32 -> bf16 conversion: X -> Xb (nxb blocks) and y0 -> ybuf1 (tail) ----
__global__ void __launch_bounds__(256) cvt_kernel(const float* __restrict__ X,
                                                  unsigned short* __restrict__ Xb,
                                                  const float* __restrict__ y0,
                                                  unsigned short* __restrict__ yb1,
                                                  int nxb) {
    const int blk = blockIdx.x;
    const float* src; unsigned short* dst; size_t i;
    if (blk < nxb) { src = X;  dst = Xb;  i = ((size_t)blk * 256 + threadIdx.x) * 8; }
    else           { src = y0; dst = yb1; i = ((size_t)(blk - nxb) * 256 + threadIdx.x) * 8; }
    float4v a = *(const float4v*)(src + i);
    float4v b = *(const float4v*)(src + i + 4);
    S8U o;
    o.u[0] = f2bf(a[0]); o.u[1] = f2bf(a[1]); o.u[2] = f2bf(a[2]); o.u[3] = f2bf(a[3]);
    o.u[4] = f2bf(b[0]); o.u[5] = f2bf(b[1]); o.u[6] = f2bf(b[2]); o.u[7] = f2bf(b[3]);
    *(short8*)(dst + i) = o.v;
}

// ---- fused persistent kernel: blocks 0..127 = scanners, 128..255 = feeders ----
template<int XBF>
__global__ void __launch_bounds__(256, 1)
lstm_fused(const float* __restrict__ X, const unsigned short* __restrict__ Xb,
           const float* __restrict__ W, const float* __restrict__ bias,
           const float* __restrict__ y0, const float* __restrict__ c0,
           const float* __restrict__ imask, float* __restrict__ out,
           unsigned* __restrict__ prog, float* __restrict__ zring)
{
    extern __shared__ char smem[];
    unsigned short* Wl = (unsigned short*)smem;            // [32][WLDH] bf16
    float* zl = (float*)(smem + 32 * WLDH * 2);            // [4][64][33] z partials (per wave)
    float* cl = zl + 4 * 64 * 33;                          // [64][8]
    float* bl = cl + 64 * 8;                               // [32]

    const int bid = blockIdx.x;
    const bool is_scan = bid < NSCAN;
    const int g   = is_scan ? bid : bid - NSCAN;
    const int tid = threadIdx.x;

    // --- W slice -> LDS bf16.  Scan: Wh rows (k+1024); feeder: Wx rows (k).
    {
        const int kbase = is_scan ? NIN : 0;
        for (int task = tid; task < 1024 * 4; task += 256) {
            int k = task >> 2, gt = task & 3;
            const float* src = W + (size_t)(kbase + k) * NGC + (size_t)gt * HB + (size_t)g * HC;
            #pragma unroll
            for (int c = 0; c < 8; ++c)
                Wl[(gt * 8 + c) * WLDH + k] = f2bf(src[c]);
        }
    }
    if (is_scan) {
        if (tid < 32) {
            int gt = tid >> 3, c = tid & 7;
            bl[tid] = bias[gt * HB + g * HC + c];
        }
        for (int p = tid; p < 512; p += 256) {
            int r = p >> 3, c = p & 7;
            cl[r * 8 + c] = c0[(size_t)r * HB + g * HC + c];
        }
    }
    __syncthreads();

    const int w = tid >> 6, l = tid & 63;
    const int m16 = l & 15, q = l >> 4;
    const int koff = q * 8;

    if (!is_scan) {
        // ================= FEEDER: Zx[t] cols [g*32, g*32+32) into ring =================
        const unsigned short* wl0 = Wl + (size_t)m16 * WLDH + koff;         // cols 0..15
        const unsigned short* wl1 = Wl + (size_t)(16 + m16) * WLDH + koff;  // cols 16..31
        const int arow = w * 16 + m16;
        unsigned* fslot = prog + NSCAN + g;
        unsigned* sslot = prog + g;
        for (int t = 0; t < T_STEPS; ++t) {
            float4v acc0 = {0.f, 0.f, 0.f, 0.f};
            float4v acc1 = {0.f, 0.f, 0.f, 0.f};
            if (XBF) {
                const unsigned short* xs = Xb + ((size_t)t * BB + arow) * NIN + koff;
                short8 abuf[8];
                #pragma unroll
                for (int p = 0; p < 8; ++p) abuf[p] = *(const short8*)(xs + p * 32);
                #pragma unroll
                for (int kb = 0; kb < 32; ++kb) {
                    short8 a = abuf[kb & 7];
                    if (kb + 8 < 32) abuf[kb & 7] = *(const short8*)(xs + (kb + 8) * 32);
                    short8 b0 = *(const short8*)(wl0 + kb * 32);
                    short8 b1 = *(const short8*)(wl1 + kb * 32);
                    acc0 = __builtin_amdgcn_mfma_f32_16x16x32_bf16(a, b0, acc0, 0, 0, 0);
                    acc1 = __builtin_amdgcn_mfma_f32_16x16x32_bf16(a, b1, acc1, 0, 0, 0);
                }
            } else {
                const float* xs = X + ((size_t)t * BB + arow) * NIN + koff;
                float4v fbv0[4], fbv1[4];
                #pragma unroll
                for (int p = 0; p < 4; ++p) {
                    fbv0[p] = *(const float4v*)(xs + p * 32);
                    fbv1[p] = *(const float4v*)(xs + p * 32 + 4);
                }
                #pragma unroll
                for (int kb = 0; kb < 32; ++kb) {
                    float4v f0 = fbv0[kb & 3], f1 = fbv1[kb & 3];
                    if (kb + 4 < 32) {
                        fbv0[kb & 3] = *(const float4v*)(xs + (kb + 4) * 32);
                        fbv1[kb & 3] = *(const float4v*)(xs + (kb + 4) * 32 + 4);
                    }
                    S8U o;
                    o.u[0] = f2bf(f0[0]); o.u[1] = f2bf(f0[1]); o.u[2] = f2bf(f0[2]); o.u[3] = f2bf(f0[3]);
                    o.u[4] = f2bf(f1[0]); o.u[5] = f2bf(f1[1]); o.u[6] = f2bf(f1[2]); o.u[7] = f2bf(f1[3]);
                    short8 b0 = *(const short8*)(wl0 + kb * 32);
                    short8 b1 = *(const short8*)(wl1 + kb * 32);
                    acc0 = __builtin_amdgcn_mfma_f32_16x16x32_bf16(o.v, b0, acc0, 0, 0, 0);
                    acc1 = __builtin_amdgcn_mfma_f32_16x16x32_bf16(o.v, b1, acc1, 0, 0, 0);
                }
            }
            // anti-overwrite: ring slot t%DRING must be past scanner's consumption
            if (t >= DRING) {
                if (tid == 0) {
                    const unsigned tgt = (unsigned)(t - DRING + 1);
                    unsigned v;
                    while (1) {
                        asm volatile("global_load_dword %0, %1, off sc0 sc1\n\t"
                                     "s_waitcnt vmcnt(0)" : "=v"(v) : "v"(sslot) : "memory");
                        if (v >= tgt) break;
                        __builtin_amdgcn_s_sleep(2);
                    }
                }
                __syncthreads();
            }
            // store 64x32 f32 slice (C/D layout: col=m16(+16), row=w*16+q*4+i2)
            float* zdst = zring + ((size_t)(t % DRING) * NSCAN + g) * 2048;
            #pragma unroll
            for (int i2 = 0; i2 < 4; ++i2) {
                float* p0 = zdst + (size_t)(w * 16 + q * 4 + i2) * 32 + m16;
                asm volatile("global_store_dword %0, %1, off sc0 sc1" :: "v"(p0), "v"(acc0[i2]) : "memory");
                asm volatile("global_store_dword %0, %1, off offset:64 sc0 sc1" :: "v"(p0), "v"(acc1[i2]) : "memory");
            }
            asm volatile("s_waitcnt vmcnt(0)" ::: "memory");
            __syncthreads();
            if (tid == 0) {
                unsigned v = (unsigned)(t + 1);
                asm volatile("global_store_dword %0, %1, off sc0 sc1" :: "v"(fslot), "v"(v) : "memory");
            }
        }
        return;
    }

    // ================= SCANNER (k-split by wave: wave w owns k in [256w, 256w+256)) =================
    float* Yout  = out;
    float* Cout  = out + (size_t)T_STEPS * BB * HB;
    float* cTout = Cout + (size_t)T_STEPS * BB * HB;
    unsigned short* yb0 = (unsigned short*)cTout;          // ybuf double-buffer aliases cT region
    unsigned short* yb1 = yb0 + BB * HB;

    const int K0 = w * 256;                                // this wave's k-window base (elems)
    const unsigned short* wlA = Wl + (size_t)m16 * WLDH + K0 + koff;        // cols 0..15
    const unsigned short* wlB = Wl + (size_t)(16 + m16) * WLDH + K0 + koff; // cols 16..31
    float* zlw = zl + w * (64 * 33);                       // this wave's z partial

    const int gr = tid >> 2;            // gate-phase row 0..63
    const int gc = (tid & 3) << 1;      // gate-phase col pair 0,2,4,6

    // packed poll: lane l<32 -> producer slot 32w+l, lane 32 -> feeder flag
    const unsigned* ppf = prog + NSCAN + g;
    const unsigned* pollad = (l < 32) ? (prog + 32 * w + l) : ppf;
    const unsigned* pp0 = prog + l;                        // sentinel-poll addrs (wave0 use)
    const unsigned* pp1 = prog + 64 + l;

    for (int t = 0; t < T_STEPS; ++t) {
        float mrow = imask[(size_t)t * BB + gr];   // cached, read-only

        // ---- Wh fragments for this wave's k-window: issue LDS reads BEFORE the poll ----
        short8 bf0[8], bf1[8];
        #pragma unroll
        for (int k2 = 0; k2 < 8; ++k2) {
            bf0[k2] = *(const short8*)(wlA + k2 * 32);
            bf1[k2] = *(const short8*)(wlB + k2 * 32);
        }

        // ---- packed per-wave poll: 33 lanes x 1 dword per iteration ----
        {
            const unsigned st = (unsigned)t, ft = (unsigned)(t + 1);
            bool ok = true;
            while (1) {
                if (l < 33) {
                    unsigned v;
                    asm volatile("global_load_dword %0, %1, off sc0 sc1" : "=v"(v) : "v"(pollad));
                    asm volatile("s_waitcnt vmcnt(0)" ::: "memory");
                    ok = (v >= ((l < 32) ? st : ft));
                }
                if (__ballot(ok) == ~0ull) break;
                __builtin_amdgcn_s_sleep(1);
            }
        }

        // ---- y_{t-1} loads: 4 row-groups x 8 k-chunks of this wave's window (MALL bypass) ----
        const unsigned short* ybase = ((t & 1) ? yb0 : yb1);
        const unsigned short* p0 = ybase + (size_t)m16 * HB + K0 + koff;
        const unsigned short* p1 = p0 + 16 * HB;
        const unsigned short* p2 = p0 + 32 * HB;
        const unsigned short* p3 = p0 + 48 * HB;
        short8 yA[8], yB[8], yC[8], yD[8];
        #pragma unroll
        for (int k2 = 0; k2 < 8; ++k2) {
            asm volatile("global_load_dwordx4 %0, %1, off offset:%2 sc0 sc1" : "=v"(yA[k2]) : "v"(p0), "i"(k2 * 64));
            asm volatile("global_load_dwordx4 %0, %1, off offset:%2 sc0 sc1" : "=v"(yB[k2]) : "v"(p1), "i"(k2 * 64));
            asm volatile("global_load_dwordx4 %0, %1, off offset:%2 sc0 sc1" : "=v"(yC[k2]) : "v"(p2), "i"(k2 * 64));
            asm volatile("global_load_dwordx4 %0, %1, off offset:%2 sc0 sc1" : "=v"(yD[k2]) : "v"(p3), "i"(k2 * 64));
        }
        // ---- Zx[t] register loads (consumed in gates; land under y latency) ----
        const float* zp = zring + ((size_t)(t % DRING) * NSCAN + g) * 2048 + (size_t)gr * 32 + gc;
        float2v zx0, zx1, zx2, zx3;
        asm volatile("global_load_dwordx2 %0, %1, off sc0 sc1"            : "=v"(zx0) : "v"(zp));
        asm volatile("global_load_dwordx2 %0, %1, off offset:32 sc0 sc1"  : "=v"(zx1) : "v"(zp));
        asm volatile("global_load_dwordx2 %0, %1, off offset:64 sc0 sc1"  : "=v"(zx2) : "v"(zp));
        asm volatile("global_load_dwordx2 %0, %1, off offset:96 sc0 sc1"  : "=v"(zx3) : "v"(zp));

        asm volatile("s_waitcnt vmcnt(0) lgkmcnt(0)" ::: "memory");
        __builtin_amdgcn_sched_barrier(0);   // rule #18: keep MFMAs below the waitcnt

        // ---- 64 back-to-back MFMAs: 4 row-groups x 2 col-groups x 8 k-chunks ----
        float4v aA0 = {0.f,0.f,0.f,0.f}, aA1 = {0.f,0.f,0.f,0.f};
        float4v aB0 = {0.f,0.f,0.f,0.f}, aB1 = {0.f,0.f,0.f,0.f};
        float4v aC0 = {0.f,0.f,0.f,0.f}, aC1 = {0.f,0.f,0.f,0.f};
        float4v aD0 = {0.f,0.f,0.f,0.f}, aD1 = {0.f,0.f,0.f,0.f};
        #pragma unroll
        for (int k2 = 0; k2 < 8; ++k2) {
            short8 b0 = bf0[k2], b1 = bf1[k2];
            aA0 = __builtin_amdgcn_mfma_f32_16x16x32_bf16(yA[k2], b0, aA0, 0, 0, 0);
            aA1 = __builtin_amdgcn_mfma_f32_16x16x32_bf16(yA[k2], b1, aA1, 0, 0, 0);
            aB0 = __builtin_amdgcn_mfma_f32_16x16x32_bf16(yB[k2], b0, aB0, 0, 0, 0);
            aB1 = __builtin_amdgcn_mfma_f32_16x16x32_bf16(yB[k2], b1, aB1, 0, 0, 0);
            aC0 = __builtin_amdgcn_mfma_f32_16x16x32_bf16(yC[k2], b0, aC0, 0, 0, 0);
            aC1 = __builtin_amdgcn_mfma_f32_16x16x32_bf16(yC[k2], b1, aC1, 0, 0, 0);
            aD0 = __builtin_amdgcn_mfma_f32_16x16x32_bf16(yD[k2], b0, aD0, 0, 0, 0);
            aD1 = __builtin_amdgcn_mfma_f32_16x16x32_bf16(yD[k2], b1, aD1, 0, 0, 0);
        }

        // ---- z partial -> LDS (C/D layout: col=m16(+16), row=rg*16+q*4+i2) ----
        #pragma unroll
        for (int i2 = 0; i2 < 4; ++i2) {
            zlw[( 0 + q * 4 + i2) * 33 + m16]      = aA0[i2];
            zlw[( 0 + q * 4 + i2) * 33 + 16 + m16] = aA1[i2];
            zlw[(16 + q * 4 + i2) * 33 + m16]      = aB0[i2];
            zlw[(16 + q * 4 + i2) * 33 + 16 + m16] = aB1[i2];
            zlw[(32 + q * 4 + i2) * 33 + m16]      = aC0[i2];
            zlw[(32 + q * 4 + i2) * 33 + 16 + m16] = aC1[i2];
            zlw[(48 + q * 4 + i2) * 33 + m16]      = aD0[i2];
            zlw[(48 + q * 4 + i2) * 33 + 16 + m16] = aD1[i2];
        }
        __syncthreads();

        // ---- last step: cT region aliases ybuf — wait until ALL scanners finished y reads ----
        if (t == T_STEPS - 1) {
            if (tid == 0) {
                unsigned v = (unsigned)(T_STEPS + 1);   // sentinel 513
                asm volatile("global_store_dword %0, %1, off sc0 sc1" :: "v"(prog + g), "v"(v) : "memory");
            }
            if (tid < 64) {
                unsigned a0, a1;
                const unsigned st = (unsigned)(T_STEPS + 1);
                while (1) {
                    asm volatile("global_load_dword %0, %1, off sc0 sc1" : "=v"(a0) : "v"(pp0));
                    asm volatile("global_load_dword %0, %1, off sc0 sc1" : "=v"(a1) : "v"(pp1));
                    asm volatile("s_waitcnt vmcnt(0)" ::: "memory");
                    bool ok = (a0 >= st) & (a1 >= st);
                    if (__ballot(ok) == ~0ull) break;
                    __builtin_amdgcn_s_sleep(2);
                }
            }
            __syncthreads();
        }

        // ---- gates: thread -> (row gr, cols gc, gc+1); z = sum of 4 wave partials + zx + bias ----
        {
            const int r = gr, c = gc;
            const int rb = r * 33;
            #define ZS(o) (zl[(o)] + zl[2112 + (o)] + zl[4224 + (o)] + zl[6336 + (o)])
            float z00 = ZS(rb + c)      + zx0[0] + bl[c];
            float z01 = ZS(rb + c + 1)  + zx0[1] + bl[c + 1];
            float z10 = ZS(rb + 8 + c)  + zx1[0] + bl[8 + c];
            float z11 = ZS(rb + 9 + c)  + zx1[1] + bl[9 + c];
            float z20 = ZS(rb + 16 + c) + zx2[0] + bl[16 + c];
            float z21 = ZS(rb + 17 + c) + zx2[1] + bl[17 + c];
            float z30 = ZS(rb + 24 + c) + zx3[0] + bl[24 + c];
            float z31 = ZS(rb + 25 + c) + zx3[1] + bl[25 + c];
            #undef ZS
            float cp0 = cl[r * 8 + c], cp1 = cl[r * 8 + c + 1];
            float m = mrow;
            float cell0 = tanhf(z00),                 cell1 = tanhf(z01);
            float ig0 = 1.f / (1.f + __expf(-z10)),   ig1 = 1.f / (1.f + __expf(-z11));
            float fg0 = 1.f / (1.f + __expf(-z20)),   fg1 = 1.f / (1.f + __expf(-z21));
            float og0 = 1.f / (1.f + __expf(-z30)),   og1 = 1.f / (1.f + __expf(-z31));
            float cn0 = cell0 * ig0 + cp0 * fg0,      cn1 = cell1 * ig1 + cp1 * fg1;
            float yn0 = tanhf(cn0) * og0,             yn1 = tanhf(cn1) * og1;  // y from pre-mask c
            cn0 = m * cn0 + (1.f - m) * cp0;          cn1 = m * cn1 + (1.f - m) * cp1;
            yn0 *= m;                                 yn1 *= m;
            cl[r * 8 + c] = cn0; cl[r * 8 + c + 1] = cn1;

            if (t < T_STEPS - 1) {
                // publish y_t bf16 (write-through to MALL), ack, then slot-signal
                unsigned short* ybw = ((t & 1) ? yb1 : yb0) + (size_t)r * HB + (size_t)g * HC + c;
                unsigned pk = (unsigned)f2bf(yn0) | ((unsigned)f2bf(yn1) << 16);
                asm volatile("global_store_dword %0, %1, off sc0 sc1" :: "v"(ybw), "v"(pk) : "memory");
                asm volatile("s_waitcnt vmcnt(0)" ::: "memory");
                __syncthreads();
                if (tid == 0) {
                    unsigned v = (unsigned)(t + 1);
                    asm volatile("global_store_dword %0, %1, off sc0 sc1" :: "v"(prog + g), "v"(v) : "memory");
                }
            }

            // fp32 outputs: cached stores, off the critical path
            size_t oidx = ((size_t)t * BB + r) * HB + (size_t)g * HC + c;
            float2v yv = {yn0, yn1}; *(float2v*)(Yout + oidx) = yv;
            float2v cv = {cn0, cn1}; *(float2v*)(Cout + oidx) = cv;
            if (t == T_STEPS - 1) {
                float2v ct = {cn0, cn1};
                *(float2v*)(cTout + (size_t)r * HB + (size_t)g * HC + c) = ct;
            }
        }
    }
}

extern "C" void kernel_launch(void* const* d_in, const int* in_sizes, int n_in,
                              void* d_out, int out_size, void* d_ws, size_t ws_size,
                              hipStream_t stream) {
    const float* X    = (const float*)d_in[0];
    const float* W    = (const float*)d_in[1];
    const float* bias = (const float*)d_in[2];
    const float* y0   = (const float*)d_in[3];
    const float* c0   = (const float*)d_in[4];
    const float* im   = (const float*)d_in[5];
    float* out = (float*)d_out;

    unsigned* prog = (unsigned*)d_ws;                               // [256] progress slots
    float* zring   = (float*)((char*)d_ws + 4096);                  // [DRING][128][64][32] f32 = 16 MB
    const size_t zbytes = (size_t)DRING * NSCAN * 2048 * 4;
    unsigned short* Xb = (unsigned short*)((char*)d_ws + 4096 + zbytes);
    const size_t xbytes = (size_t)T_STEPS * BB * NIN * sizeof(unsigned short);   // 64 MB
    const int use_bf = (ws_size >= 4096 + zbytes + xbytes) ? 1 : 0;

    // ybuf double-buffer aliases the cT region of out (exact 256 KB fit)
    unsigned short* yb1 = (unsigned short*)(out + (size_t)2 * T_STEPS * BB * HB) + (size_t)BB * HB;

    const int smem_bytes = 32 * WLDH * 2 + 4 * 64 * 33 * 4 + 64 * 8 * 4 + 32 * 4;  // 102,016 B

    hipMemsetAsync(d_ws, 0, 4096, stream);   // zero progress slots (ws poisoned each launch)

    const int nxb = use_bf ? (T_STEPS * BB * NIN) / (256 * 8) : 0;  // 16384 or 0
    const int nyb = (BB * HB) / (256 * 8);                          // 32
    cvt_kernel<<<nxb + nyb, 256, 0, stream>>>(X, Xb, y0, yb1, nxb);

    if (use_bf) {
        hipFuncSetAttribute((const void*)lstm_fused<1>,
                            hipFuncAttributeMaxDynamicSharedMemorySize, smem_bytes);
        lstm_fused<1><<<2 * NSCAN, 256, smem_bytes, stream>>>(X, Xb, W, bias, y0, c0, im, out, prog, zring);
    } else {
        hipFuncSetAttribute((const void*)lstm_fused<0>,
                            hipFuncAttributeMaxDynamicSharedMemorySize, smem_bytes);
        lstm_fused<0><<<2 * NSCAN, 256, smem_bytes, stream>>>(X, Xb, W, bias, y0, c0, im, out, prog, zring);
    }
}